// Round 12
// baseline (85.097 us; speedup 1.0000x reference)
//
#include <hip/hip_runtime.h>
#include <hip/hip_bf16.h>

// MHSA: x(2,512,2048) f32, 8 heads x 64. All heavy math in bf16 MFMA 16x16x32.
// Pipeline: prep(xpose+wconv) -> gemm_bt<0>(fused QKV) -> attn(kv-split 4) -> gemm_out(merge+proj)
// attn: XCD-swizzled; swapped QK^T/PV; fixed-shift softmax (exact); K+V double-buffered via
//       global_load_lds; SINGLE barrier/iter (wait-then-issue); 48KB LDS -> 3 blocks/CU.
// gemm_out: merge (sum 4 bf16 partials / L) fused into A-staging; BK chunk == one head.

typedef __attribute__((ext_vector_type(8))) short short8;   // 8 bf16 = 4 VGPR (MFMA A/B frag)
typedef __attribute__((ext_vector_type(4))) short short4v;  // 4 bf16 (8B store)
typedef __attribute__((ext_vector_type(4))) float f32x4;    // MFMA C/D frag
typedef __attribute__((ext_vector_type(2))) int int2v;      // 8B LDS store
typedef __attribute__((ext_vector_type(4))) int int4v;      // 16B LDS store

#define DEV static __device__ __forceinline__

DEV short f2bf(float f) {  // fp32 -> bf16 RNE
  union { float f; unsigned u; } v; v.f = f;
  unsigned r = (v.u + 0x7FFFu + ((v.u >> 16) & 1u)) >> 16;
  return (short)r;
}

DEV float bf2f(short s) {  // bf16 -> fp32 (exact)
  union { unsigned u; float f; } v;
  v.u = ((unsigned)(unsigned short)s) << 16;
  return v.f;
}

DEV unsigned pk_bf16(float lo, float hi) {  // compiler emits v_cvt_pk_bf16_f32 (RNE)
  union { __hip_bfloat162 h; unsigned u; } cv;
  cv.h = __float22bfloat162_rn(float2{lo, hi});
  return cv.u;
}

DEV void gload_lds16(const void* g, void* l) {
  // wave-uniform LDS base; HW writes lane*16B
  __builtin_amdgcn_global_load_lds((const __attribute__((address_space(1))) void*)g,
                                   (__attribute__((address_space(3))) void*)l, 16, 0, 0);
}

// ---------------- prep: [bid<2048] x (B,512,2048) f32 -> XT[(b*2048+s)][512] bf16
//                  [bid>=2048] weights f32 -> bf16 concat [wq|wk|wv|wo] ----------------
__global__ __launch_bounds__(256) void prep_k(const float* __restrict__ x, short* __restrict__ xt,
                                              const float* __restrict__ wq, const float* __restrict__ wk,
                                              const float* __restrict__ wv, const float* __restrict__ wo,
                                              short* __restrict__ wdst) {
  __shared__ float tile[32][33];
  const int bid = blockIdx.x;
  if (bid < 2048) {
    const int b = bid >> 10, rest = bid & 1023;
    const int s0 = (rest & 63) * 32, c0 = (rest >> 6) * 32;
    const int tl = threadIdx.x & 31, tr = threadIdx.x >> 5;  // tr 0..7
    const float* src = x + ((size_t)b * 512 + c0) * 2048 + s0;
#pragma unroll
    for (int i = 0; i < 4; ++i)
      tile[tr + i * 8][tl] = src[(size_t)(tr + i * 8) * 2048 + tl];  // tile[c][s]
    __syncthreads();
    short* dst = xt + ((size_t)b * 2048 + s0) * 512 + c0;
#pragma unroll
    for (int i = 0; i < 4; ++i) {
      const int s = tr + i * 8;
      dst[(size_t)s * 512 + tl] = f2bf(tile[tl][s]);
    }
  } else {
    const int idx = (bid - 2048) * 256 + threadIdx.x;  // 262144 threads, 4 elems each
    const int m = idx >> 16;
    const int base = (idx & 65535) * 4;
    const float* src = (m == 0) ? wq : (m == 1) ? wk : (m == 2) ? wv : wo;
    const f32x4 v = *(const f32x4*)(src + base);
    short4v o;
#pragma unroll
    for (int r = 0; r < 4; ++r) o[r] = f2bf(v[r]);
    *(short4v*)(wdst + (size_t)idx * 4) = o;
  }
}

// ---------------- gemm_bt<0>: fused QKV. D[i][j] = sum_k A[i][k]*B[j][k], K=512, BK=64 ----
// tile 128x128, A=Wqkv[1536][512], B=XT[4096][512], grid 384 (XCD-swizzled).
//   i<512: Q -> QKB[j*1024+i] scaled 1/8 +bq | 512..1023: K -> QKB[j*1024+i] +bk
//   i>=1024: V -> VB[(i-1024)*4096+j] +bv (transposed store)
template <int MODE>
__global__ __launch_bounds__(256) void gemm_bt_k(const short* __restrict__ A, const short* __restrict__ B,
                                                 void* __restrict__ out, short* __restrict__ out2,
                                                 const float* __restrict__ bias0,
                                                 const float* __restrict__ bias1,
                                                 const float* __restrict__ bias2) {
  constexpr int NI = 12;
  constexpr int CHUNK = 48;  // gridDim/8
  __shared__ short As[128 * 64];
  __shared__ short Bs[128 * 64];
  const int bx0 = blockIdx.x;
  const int bx = (bx0 & 7) * CHUNK + (bx0 >> 3);  // XCD-contiguous chunks
  const int it = bx % NI, jt = bx / NI;
  const int tid = threadIdx.x;
  const int lane = tid & 63, wid = tid >> 6;
  const int wi = wid & 1, wj = wid >> 1;
  const int g = lane >> 4, c = lane & 15;

  f32x4 acc[4][4] = {};

  for (int k0 = 0; k0 < 512; k0 += 64) {
#pragma unroll
    for (int q = 0; q < 4; ++q) {
      const int blk = wid * 4 + q;              // 16 blocks of 8 rows
      const int row = blk * 8 + (lane >> 3);
      const int ks = ((lane & 7) ^ (row & 7)) * 8;
      gload_lds16(A + (size_t)(it * 128 + row) * 512 + k0 + ks, As + blk * 512);
      gload_lds16(B + (size_t)(jt * 128 + row) * 512 + k0 + ks, Bs + blk * 512);
    }
    __syncthreads();
#pragma unroll
    for (int kk = 0; kk < 2; ++kk) {
      short8 af[4], bfv[4];
#pragma unroll
      for (int mi = 0; mi < 4; ++mi) {
        const int row = wi * 64 + mi * 16 + c;
        af[mi] = *(const short8*)(As + ((row * 64 + kk * 32 + g * 8) ^ ((row & 7) << 3)));
      }
#pragma unroll
      for (int nj = 0; nj < 4; ++nj) {
        const int row = wj * 64 + nj * 16 + c;
        bfv[nj] = *(const short8*)(Bs + ((row * 64 + kk * 32 + g * 8) ^ ((row & 7) << 3)));
      }
#pragma unroll
      for (int mi = 0; mi < 4; ++mi)
#pragma unroll
        for (int nj = 0; nj < 4; ++nj)
          acc[mi][nj] = __builtin_amdgcn_mfma_f32_16x16x32_bf16(af[mi], bfv[nj], acc[mi][nj], 0, 0, 0);
    }
    __syncthreads();
  }

  short* ob = (short*)out;
#pragma unroll
  for (int mi = 0; mi < 4; ++mi) {
    const int i0 = it * 128 + wi * 64 + mi * 16 + g * 4;  // wave-uniform range per mi
    if (i0 < 1024) {  // Q or K -> QKB[j*1024 + i]
      const bool isQ = i0 < 512;
      const float scale = isQ ? 0.125f : 1.0f;  // fold 1/sqrt(hd)=1/8 into Q
      const float* bp = isQ ? bias0 : bias1;
      const int boff = isQ ? 0 : 512;
      float b4[4];
#pragma unroll
      for (int r = 0; r < 4; ++r) b4[r] = bp[i0 + r - boff];
#pragma unroll
      for (int nj = 0; nj < 4; ++nj) {
        const int j = jt * 128 + wj * 64 + nj * 16 + c;
        short4v st;
#pragma unroll
        for (int r = 0; r < 4; ++r) st[r] = f2bf((acc[mi][nj][r] + b4[r]) * scale);
        *(short4v*)(ob + (size_t)j * 1024 + i0) = st;
      }
    } else {  // V -> VB[(i-1024)*4096 + j] (transposed scalar stores, 16-lane contiguous)
      float b4[4];
#pragma unroll
      for (int r = 0; r < 4; ++r) b4[r] = bias2[i0 + r - 1024];
#pragma unroll
      for (int nj = 0; nj < 4; ++nj) {
        const int j = jt * 128 + wj * 64 + nj * 16 + c;
#pragma unroll
        for (int r = 0; r < 4; ++r)
          out2[(size_t)(i0 + r - 1024) * 4096 + j] = f2bf(acc[mi][nj][r] + b4[r]);
      }
    }
  }
}

// ---------------- attention (kv-split): per (b,h,seg), flash over 8 kv tiles of 64 ----
// Grid 1D 1024, XCD-swizzled. Swapped QK^T/PV; fixed-shift softmax P=e^(s-4) (exact).
// SINGLE barrier/iter: wait vmcnt(0) (only K[t],V[t] outstanding -> counted-equivalent) + barrier
// at loop top; the same barrier proves all waves finished last iter's reads of buf^1, so the
// subsequent DMA issue into buf^1 is safe and the end-of-iter barrier is removed.
__global__ __launch_bounds__(256, 4) void attn_k(const short* __restrict__ qk, const short* __restrict__ v,
                                                 short* __restrict__ OPB, float* __restrict__ Lb) {
  __shared__ short ks2[2][64 * 64];   // K tile [s][d], swizzled, double-buffered (16KB)
  __shared__ short vs2[2][64 * 64];   // V tile [d][s], swizzled, double-buffered (16KB)
  __shared__ short pbuf[4][32 * 64];  // per-wave P [t][s], swizzled              (16KB)
  const int bid = blockIdx.x;                       // 0..1023
  const int swz = (bid & 7) * 128 + (bid >> 3);     // XCD-contiguous chunks of 128
  const int qt = swz & 15;                          // fastest within chunk
  const int grp = swz >> 4;                         // (bh,seg) group, 8 per XCD
  const int bh = grp & 15, seg = grp >> 4;
  const int b = bh >> 3, h = bh & 7;
  const int lane = threadIdx.x & 63, wid = threadIdx.x >> 6;
  const int g = lane >> 4, c = lane & 15;
  const int q0 = qt * 128 + wid * 32;
  short* pl = pbuf[wid];

  const short* qp = qk + (size_t)(b * 2048 + q0) * 1024 + h * 64;
  const short* kb = qk + (size_t)(b * 2048) * 1024 + 512 + h * 64;
  const short* vb = v + (size_t)(h * 64) * 4096 + b * 2048;

  // Q as B-operand frags (rows t, once per block)
  short8 qf[2][2];
#pragma unroll
  for (int nj = 0; nj < 2; ++nj)
#pragma unroll
    for (int kk = 0; kk < 2; ++kk)
      qf[nj][kk] = *(const short8*)(qp + (size_t)(nj * 16 + c) * 1024 + kk * 32 + g * 8);

  // staging geometry: row-of-8 blocks, XOR-pre-swizzled source column (16B granules)
  const int sr = lane >> 3;                 // 0..7 (== row&7)
  const int scol = ((lane & 7) ^ sr) * 8;   // shorts

  const int kvbeg = seg * 512;
  // prologue: issue K[0], V[0] -> buf 0 (4 loads outstanding)
#pragma unroll
  for (int q = 0; q < 2; ++q) {
    const int blk = wid * 2 + q;
    const int row = blk * 8 + sr;
    gload_lds16(kb + (size_t)(kvbeg + row) * 1024 + scol, &ks2[0][blk * 512]);
    gload_lds16(vb + (size_t)row * 4096 + kvbeg + scol, &vs2[0][blk * 512]);
  }

  f32x4 oacc[4][2] = {};      // [dj][o]: O^T rows d=dj*16+g*4+r, col t=o*16+c
  float lpart[2] = {0.f, 0.f};
  const float LOG2E = 1.44269504088896f;
  const float M2 = 5.770780163555852f;  // 4*log2(e): fixed softmax shift (exact)

  for (int it8 = 0; it8 < 8; ++it8) {
    const int bufi = it8 & 1;

    // (1) K[t],V[t] ready (only outstanding loads) + all waves done reading buf^1
    asm volatile("s_waitcnt vmcnt(0)" ::: "memory");
    __builtin_amdgcn_s_barrier();

    // (2) issue K[t+1], V[t+1] -> buf^1 (wrapped at t=7: count-invariant, target never read)
    {
      const int kvn = kvbeg + ((it8 + 1) & 7) * 64;
#pragma unroll
      for (int q = 0; q < 2; ++q) {
        const int blk = wid * 2 + q;
        const int row = blk * 8 + sr;
        gload_lds16(kb + (size_t)(kvn + row) * 1024 + scol, &ks2[bufi ^ 1][blk * 512]);
        gload_lds16(vb + (size_t)row * 4096 + kvn + scol, &vs2[bufi ^ 1][blk * 512]);
      }
    }

    // (3) QK^T swapped: S^T[mi][nj], rows s=mi*16+g*4+r, col t=nj*16+c
    f32x4 st[4][2] = {};
    __builtin_amdgcn_s_setprio(1);
#pragma unroll
    for (int kk = 0; kk < 2; ++kk) {
      short8 kf[4];
#pragma unroll
      for (int mi = 0; mi < 4; ++mi) {
        const int row = mi * 16 + c;
        kf[mi] = *(const short8*)(&ks2[bufi][(row * 64 + kk * 32 + g * 8) ^ ((row & 7) << 3)]);
      }
#pragma unroll
      for (int mi = 0; mi < 4; ++mi)
#pragma unroll
        for (int nj = 0; nj < 2; ++nj)
          st[mi][nj] = __builtin_amdgcn_mfma_f32_16x16x32_bf16(kf[mi], qf[nj][kk], st[mi][nj], 0, 0, 0);
    }
    __builtin_amdgcn_s_setprio(0);

    // (4) P = exp2(s*LOG2E - M2) = e^(s-4); pack bf16; swizzled 8B stores to pbuf[t][s]
#pragma unroll
    for (int mi = 0; mi < 4; ++mi)
#pragma unroll
      for (int nj = 0; nj < 2; ++nj) {
        const float p0 = __builtin_amdgcn_exp2f(__builtin_fmaf(st[mi][nj][0], LOG2E, -M2));
        const float p1 = __builtin_amdgcn_exp2f(__builtin_fmaf(st[mi][nj][1], LOG2E, -M2));
        const float p2 = __builtin_amdgcn_exp2f(__builtin_fmaf(st[mi][nj][2], LOG2E, -M2));
        const float p3 = __builtin_amdgcn_exp2f(__builtin_fmaf(st[mi][nj][3], LOG2E, -M2));
        lpart[nj] += (p0 + p1) + (p2 + p3);
        const unsigned w0 = pk_bf16(p0, p1);
        const unsigned w1 = pk_bf16(p2, p3);
        const int t = nj * 16 + c;
        *(int2v*)(pl + ((t * 64 + mi * 16 + g * 4) ^ ((t & 7) << 3))) = (int2v){(int)w0, (int)w1};
      }

    // (5) PV swapped: O^T[dj][o] += V^T-frag(dj) x P-frag(o)
    __builtin_amdgcn_s_setprio(1);
#pragma unroll
    for (int kk = 0; kk < 2; ++kk) {
      short8 vf[4], pa[2];
#pragma unroll
      for (int dj = 0; dj < 4; ++dj) {
        const int row = dj * 16 + c;
        vf[dj] = *(const short8*)(&vs2[bufi][(row * 64 + kk * 32 + g * 8) ^ ((row & 7) << 3)]);
      }
#pragma unroll
      for (int o = 0; o < 2; ++o) {
        const int row = o * 16 + c;
        pa[o] = *(const short8*)(pl + ((row * 64 + kk * 32 + g * 8) ^ ((row & 7) << 3)));
      }
#pragma unroll
      for (int dj = 0; dj < 4; ++dj)
#pragma unroll
        for (int o = 0; o < 2; ++o)
          oacc[dj][o] = __builtin_amdgcn_mfma_f32_16x16x32_bf16(vf[dj], pa[o], oacc[dj][o], 0, 0, 0);
    }
    __builtin_amdgcn_s_setprio(0);
    // no end-of-iter barrier: next iter's top barrier orders buf reuse
  }

  // epilogue: row sums (reduce over g-groups once), unnormalized O^T -> OPB (bf16, 8B stores)
  float lrow[2];
#pragma unroll
  for (int nj = 0; nj < 2; ++nj) {
    float a = lpart[nj];
    a += __shfl_xor(a, 16);
    a += __shfl_xor(a, 32);
    lrow[nj] = a;
  }
  const size_t rbase = (size_t)seg * 32768 + (size_t)bh * 2048 + q0;
#pragma unroll
  for (int o = 0; o < 2; ++o) {
    const int t = o * 16 + c;
#pragma unroll
    for (int dj = 0; dj < 4; ++dj) {
      short4v w;
#pragma unroll
      for (int r = 0; r < 4; ++r) w[r] = f2bf(oacc[dj][o][r]);
      *(short4v*)(OPB + (rbase + t) * 64 + dj * 16 + g * 4) = w;
    }
    if (g == 0) Lb[rbase + t] = lrow[o];
  }
  // drain wrapped prefetch DMAs before wave exit (LDS dealloc hazard)
  asm volatile("s_waitcnt vmcnt(0)" ::: "memory");
}

// ---------------- gemm_out: fused merge + out-projection. tile 64x128, grid 256 ----
// out[b][j][t] = sum_k A[i][k] Wo[j][k] + bo[j], where A[i=(b,t)][k=h*64+d]
//             = (sum_seg OPB[(seg,bh,t)][d]) / L(bh,t)  -- BK=64 chunk k0=h*64 == one head.
__global__ __launch_bounds__(256) void gemm_out_k(const short* __restrict__ OPB,
                                                  const float* __restrict__ Lb,
                                                  const short* __restrict__ Bw,
                                                  float* __restrict__ out,
                                                  const float* __restrict__ bias) {
  __shared__ short As[64 * 64];
  __shared__ short Bs[128 * 64];
  const int bx0 = blockIdx.x;
  const int bx = (bx0 & 7) * 32 + (bx0 >> 3);  // XCD-contiguous chunks
  const int it = bx & 63, jt = bx >> 6;        // 64 M-tiles x 4 N-tiles
  const int tid = threadIdx.x;
  const int lane = tid & 63, wid = tid >> 6;
  const int wi = wid & 1, wj = wid >> 1;
  const int g = lane >> 4, c = lane & 15;
  const int bb = it >> 5;             // batch of this M-tile (64 rows share b)
  const int t0 = (it & 31) * 64;      // t = t0 + r
  const int ar = tid >> 2;            // staging row 0..63
  const int adq = (tid & 3) * 16;     // staging d-quarter
  const int trow = t0 + ar;

  f32x4 acc[2][4] = {};

  for (int ks = 0; ks < 8; ++ks) {
    const int bh = bb * 8 + ks;  // head == K-step
    // A reg-stage with fused merge: sum 4 segs, normalize, pack, swizzled LDS write
    {
      float L = 0.f;
#pragma unroll
      for (int s = 0; s < 4; ++s) L += Lb[(size_t)s * 32768 + bh * 2048 + trow];
      const float rinv = 1.f / L;
      float a16[16];
#pragma unroll
      for (int r = 0; r < 16; ++r) a16[r] = 0.f;
#pragma unroll
      for (int s = 0; s < 4; ++s) {
        const short* src = OPB + ((size_t)s * 32768 + bh * 2048 + trow) * 64 + adq;
        const short8 v0 = *(const short8*)(src);
        const short8 v1 = *(const short8*)(src + 8);
#pragma unroll
        for (int r = 0; r < 8; ++r) { a16[r] += bf2f(v0[r]); a16[8 + r] += bf2f(v1[r]); }
      }
      int4v w0, w1;
#pragma unroll
      for (int r = 0; r < 4; ++r) {
        w0[r] = (int)pk_bf16(a16[2 * r] * rinv, a16[2 * r + 1] * rinv);
        w1[r] = (int)pk_bf16(a16[8 + 2 * r] * rinv, a16[9 + 2 * r] * rinv);
      }
      *(int4v*)(As + ((ar * 64 + adq) ^ ((ar & 7) << 3))) = w0;
      *(int4v*)(As + ((ar * 64 + adq + 8) ^ ((ar & 7) << 3))) = w1;
    }
    // B stage via DMA: Wo rows jt*128.., k0 = ks*64
#pragma unroll
    for (int q = 0; q < 4; ++q) {
      const int blk = wid * 4 + q;
      const int row = blk * 8 + (lane >> 3);
      const int kcol = ((lane & 7) ^ (row & 7)) * 8;
      gload_lds16(Bw + (size_t)(jt * 128 + row) * 512 + ks * 64 + kcol, Bs + blk * 512);
    }
    __syncthreads();
#pragma unroll
    for (int kk = 0; kk < 2; ++kk) {
      short8 af[2], bfv[4];
#pragma unroll
      for (int mi = 0; mi < 2; ++mi) {
        const int row = wi * 32 + mi * 16 + c;
        af[mi] = *(const short8*)(As + ((row * 64 + kk * 32 + g * 8) ^ ((row & 7) << 3)));
      }
#pragma unroll
      for (int nj = 0; nj < 4; ++nj) {
        const int row = wj * 64 + nj * 16 + c;
        bfv[nj] = *(const short8*)(Bs + ((row * 64 + kk * 32 + g * 8) ^ ((row & 7) << 3)));
      }
#pragma unroll
      for (int mi = 0; mi < 2; ++mi)
#pragma unroll
        for (int nj = 0; nj < 4; ++nj)
          acc[mi][nj] = __builtin_amdgcn_mfma_f32_16x16x32_bf16(af[mi], bfv[nj], acc[mi][nj], 0, 0, 0);
    }
    __syncthreads();
  }

  // epilogue: out f32 (B,512,S), lane holds t = i0+g*4..+3 contiguous -> f32x4 stores
#pragma unroll
  for (int mi = 0; mi < 2; ++mi) {
    const int i0 = it * 64 + wi * 32 + mi * 16 + g * 4;
    const int t = i0 & 2047;
#pragma unroll
    for (int nj = 0; nj < 4; ++nj) {
      const int j = jt * 128 + wj * 64 + nj * 16 + c;
      const float bj = bias[j];
      f32x4 stv;
#pragma unroll
      for (int r = 0; r < 4; ++r) stv[r] = acc[mi][nj][r] + bj;
      *(f32x4*)(out + ((size_t)(bb * 512 + j)) * 2048 + t) = stv;
    }
  }
}

// ---------------- launcher ----------------
extern "C" void kernel_launch(void* const* d_in, const int* in_sizes, int n_in,
                              void* d_out, int out_size, void* d_ws, size_t ws_size,
                              hipStream_t stream) {
  const float* x  = (const float*)d_in[0];
  const float* wq = (const float*)d_in[1];
  const float* bq = (const float*)d_in[2];
  const float* wk = (const float*)d_in[3];
  const float* bk = (const float*)d_in[4];
  const float* wv = (const float*)d_in[5];
  const float* bv = (const float*)d_in[6];
  const float* wo = (const float*)d_in[7];
  const float* bo = (const float*)d_in[8];

  short* XT  = (short*)d_ws;                       // 4096*512 bf16
  short* WQKV = XT + (size_t)4096 * 512;           // 1536*512 (wq|wk|wv)
  short* WO  = WQKV + (size_t)1536 * 512;          // 512*512
  short* QKB = WO + (size_t)512 * 512;             // 4096*1024
  short* VB  = QKB + (size_t)4096 * 1024;          // 512*4096
  short* OPB = VB + (size_t)512 * 4096;            // 4*32768*64 bf16 partial O
  float* Lb  = (float*)(OPB + (size_t)4 * 32768 * 64);  // 4*32768 f32

  prep_k<<<dim3(3072), 256, 0, stream>>>(x, XT, wq, wk, wv, wo, WQKV);
  gemm_bt_k<0><<<dim3(384), 256, 0, stream>>>(WQKV, XT, (void*)QKB, VB, bq, bk, bv);
  attn_k<<<dim3(1024), 256, 0, stream>>>(QKB, VB, OPB, Lb);
  gemm_out_k<<<dim3(256), 256, 0, stream>>>(OPB, Lb, WO, (float*)d_out, bo);
}

// Round 13
// 73.002 us; speedup vs baseline: 1.1657x; 1.1657x over previous
//
#include <hip/hip_runtime.h>
#include <hip/hip_bf16.h>

// MHSA: x(2,512,2048) f32, 8 heads x 64. All heavy math in bf16 MFMA 16x16x32.
// Pipeline: prep(xpose+wconv) -> gemm_bt<0>(fused QKV) -> attn(kv-split 4) -> merge -> gemm_bt<2>(out)
// attn: XCD-swizzled; swapped QK^T/PV; fixed-shift softmax (exact); K+V double-buffered via
//       global_load_lds; SINGLE barrier/iter (wait-then-issue); 48KB LDS -> 3 blocks/CU.
// merge kept as separate streaming kernel (R12's fused version serialized A-staging: -10us).

typedef __attribute__((ext_vector_type(8))) short short8;   // 8 bf16 = 4 VGPR (MFMA A/B frag)
typedef __attribute__((ext_vector_type(4))) short short4v;  // 4 bf16 (8B store)
typedef __attribute__((ext_vector_type(4))) float f32x4;    // MFMA C/D frag
typedef __attribute__((ext_vector_type(2))) int int2v;      // 8B LDS store

#define DEV static __device__ __forceinline__

DEV short f2bf(float f) {  // fp32 -> bf16 RNE
  union { float f; unsigned u; } v; v.f = f;
  unsigned r = (v.u + 0x7FFFu + ((v.u >> 16) & 1u)) >> 16;
  return (short)r;
}

DEV float bf2f(short s) {  // bf16 -> fp32 (exact)
  union { unsigned u; float f; } v;
  v.u = ((unsigned)(unsigned short)s) << 16;
  return v.f;
}

DEV unsigned pk_bf16(float lo, float hi) {  // compiler emits v_cvt_pk_bf16_f32 (RNE)
  union { __hip_bfloat162 h; unsigned u; } cv;
  cv.h = __float22bfloat162_rn(float2{lo, hi});
  return cv.u;
}

DEV void gload_lds16(const void* g, void* l) {
  // wave-uniform LDS base; HW writes lane*16B
  __builtin_amdgcn_global_load_lds((const __attribute__((address_space(1))) void*)g,
                                   (__attribute__((address_space(3))) void*)l, 16, 0, 0);
}

// ---------------- prep: [bid<2048] x (B,512,2048) f32 -> XT[(b*2048+s)][512] bf16
//                  [bid>=2048] weights f32 -> bf16 concat [wq|wk|wv|wo] ----------------
__global__ __launch_bounds__(256) void prep_k(const float* __restrict__ x, short* __restrict__ xt,
                                              const float* __restrict__ wq, const float* __restrict__ wk,
                                              const float* __restrict__ wv, const float* __restrict__ wo,
                                              short* __restrict__ wdst) {
  __shared__ float tile[32][33];
  const int bid = blockIdx.x;
  if (bid < 2048) {
    const int b = bid >> 10, rest = bid & 1023;
    const int s0 = (rest & 63) * 32, c0 = (rest >> 6) * 32;
    const int tl = threadIdx.x & 31, tr = threadIdx.x >> 5;  // tr 0..7
    const float* src = x + ((size_t)b * 512 + c0) * 2048 + s0;
#pragma unroll
    for (int i = 0; i < 4; ++i)
      tile[tr + i * 8][tl] = src[(size_t)(tr + i * 8) * 2048 + tl];  // tile[c][s]
    __syncthreads();
    short* dst = xt + ((size_t)b * 2048 + s0) * 512 + c0;
#pragma unroll
    for (int i = 0; i < 4; ++i) {
      const int s = tr + i * 8;
      dst[(size_t)s * 512 + tl] = f2bf(tile[tl][s]);
    }
  } else {
    const int idx = (bid - 2048) * 256 + threadIdx.x;  // 262144 threads, 4 elems each
    const int m = idx >> 16;
    const int base = (idx & 65535) * 4;
    const float* src = (m == 0) ? wq : (m == 1) ? wk : (m == 2) ? wv : wo;
    const f32x4 v = *(const f32x4*)(src + base);
    short4v o;
#pragma unroll
    for (int r = 0; r < 4; ++r) o[r] = f2bf(v[r]);
    *(short4v*)(wdst + (size_t)idx * 4) = o;
  }
}

// ---------------- gemm_bt: D[i][j] = sum_k A[i][k]*B[j][k], K=512, BK=64 ----
// MODE 0 (fused QKV): tile 128x128, A=Wqkv[1536][512], B=XT[4096][512], grid 384 (XCD-swizzled).
//   i<512: Q -> QKB[j*1024+i] scaled 1/8 +bq | 512..1023: K -> QKB[j*1024+i] +bk
//   i>=1024: V -> VB[(i-1024)*4096+j] +bv (transposed store)
// MODE 2: tile 64x128 (256 blocks, full CU coverage), A=OB[4096][512], B=Wo[512][512]
//   -> out f32 (B,512,S) (+bias0(j)), i=(b,t)
template <int MODE>
__global__ __launch_bounds__(256) void gemm_bt_k(const short* __restrict__ A, const short* __restrict__ B,
                                                 void* __restrict__ out, short* __restrict__ out2,
                                                 const float* __restrict__ bias0,
                                                 const float* __restrict__ bias1,
                                                 const float* __restrict__ bias2) {
  constexpr int TM = (MODE == 0) ? 128 : 64;    // M-tile
  constexpr int MI = TM / 32;                   // acc rows per wave (4 or 2)
  constexpr int ABLK = TM / 32;                 // A staging blocks per wave (4 or 2)
  constexpr int NI = (MODE == 0) ? 12 : 64;     // M-tiles in grid
  constexpr int CHUNK = (MODE == 0) ? 48 : 32;  // gridDim/8, grid % 8 == 0
  __shared__ short As[TM * 64];
  __shared__ short Bs[128 * 64];
  const int bx0 = blockIdx.x;
  const int bx = (bx0 & 7) * CHUNK + (bx0 >> 3);  // XCD-contiguous chunks
  const int it = bx % NI, jt = bx / NI;
  const int tid = threadIdx.x;
  const int lane = tid & 63, wid = tid >> 6;
  const int wi = wid & 1, wj = wid >> 1;
  const int g = lane >> 4, c = lane & 15;

  f32x4 acc[MI][4] = {};

  for (int k0 = 0; k0 < 512; k0 += 64) {
#pragma unroll
    for (int q = 0; q < ABLK; ++q) {
      const int blk = wid * ABLK + q;           // TM/8 blocks of 8 rows
      const int row = blk * 8 + (lane >> 3);
      const int ks = ((lane & 7) ^ (row & 7)) * 8;
      gload_lds16(A + (size_t)(it * TM + row) * 512 + k0 + ks, As + blk * 512);
    }
#pragma unroll
    for (int q = 0; q < 4; ++q) {
      const int blk = wid * 4 + q;              // 16 blocks of 8 rows
      const int row = blk * 8 + (lane >> 3);
      const int ks = ((lane & 7) ^ (row & 7)) * 8;
      gload_lds16(B + (size_t)(jt * 128 + row) * 512 + k0 + ks, Bs + blk * 512);
    }
    __syncthreads();
#pragma unroll
    for (int kk = 0; kk < 2; ++kk) {
      short8 af[MI], bfv[4];
#pragma unroll
      for (int mi = 0; mi < MI; ++mi) {
        const int row = wi * (TM / 2) + mi * 16 + c;
        af[mi] = *(const short8*)(As + ((row * 64 + kk * 32 + g * 8) ^ ((row & 7) << 3)));
      }
#pragma unroll
      for (int nj = 0; nj < 4; ++nj) {
        const int row = wj * 64 + nj * 16 + c;
        bfv[nj] = *(const short8*)(Bs + ((row * 64 + kk * 32 + g * 8) ^ ((row & 7) << 3)));
      }
#pragma unroll
      for (int mi = 0; mi < MI; ++mi)
#pragma unroll
        for (int nj = 0; nj < 4; ++nj)
          acc[mi][nj] = __builtin_amdgcn_mfma_f32_16x16x32_bf16(af[mi], bfv[nj], acc[mi][nj], 0, 0, 0);
    }
    __syncthreads();
  }

  // epilogue: D[i][j], lane holds rows i0+g*4+r at col j (4 consecutive i -> vector store)
  if constexpr (MODE == 0) {
    short* ob = (short*)out;
#pragma unroll
    for (int mi = 0; mi < MI; ++mi) {
      const int i0 = it * 128 + wi * 64 + mi * 16 + g * 4;  // wave-uniform range per mi
      if (i0 < 1024) {  // Q or K -> QKB[j*1024 + i]
        const bool isQ = i0 < 512;
        const float scale = isQ ? 0.125f : 1.0f;  // fold 1/sqrt(hd)=1/8 into Q
        const float* bp = isQ ? bias0 : bias1;
        const int boff = isQ ? 0 : 512;
        float b4[4];
#pragma unroll
        for (int r = 0; r < 4; ++r) b4[r] = bp[i0 + r - boff];
#pragma unroll
        for (int nj = 0; nj < 4; ++nj) {
          const int j = jt * 128 + wj * 64 + nj * 16 + c;
          short4v st;
#pragma unroll
          for (int r = 0; r < 4; ++r) st[r] = f2bf((acc[mi][nj][r] + b4[r]) * scale);
          *(short4v*)(ob + (size_t)j * 1024 + i0) = st;
        }
      } else {  // V -> VB[(i-1024)*4096 + j] (transposed scalar stores, 16-lane contiguous)
        float b4[4];
#pragma unroll
        for (int r = 0; r < 4; ++r) b4[r] = bias2[i0 + r - 1024];
#pragma unroll
        for (int nj = 0; nj < 4; ++nj) {
          const int j = jt * 128 + wj * 64 + nj * 16 + c;
#pragma unroll
          for (int r = 0; r < 4; ++r)
            out2[(size_t)(i0 + r - 1024) * 4096 + j] = f2bf(acc[mi][nj][r] + b4[r]);
        }
      }
    }
  } else {
    float* ob = (float*)out;
#pragma unroll
    for (int mi = 0; mi < MI; ++mi) {
      const int i0 = it * 64 + wi * 32 + mi * 16 + g * 4;
      const int bb = i0 >> 11, t = i0 & 2047;
#pragma unroll
      for (int nj = 0; nj < 4; ++nj) {
        const int j = jt * 128 + wj * 64 + nj * 16 + c;
        const float bj = bias0[j];
        f32x4 st;
#pragma unroll
        for (int r = 0; r < 4; ++r) st[r] = acc[mi][nj][r] + bj;
        *(f32x4*)(ob + ((size_t)(bb * 512 + j)) * 2048 + t) = st;
      }
    }
  }
}

// ---------------- attention (kv-split): per (b,h,seg), flash over 8 kv tiles of 64 ----
// Grid 1D 1024, XCD-swizzled. Swapped QK^T/PV; fixed-shift softmax P=e^(s-4) (exact).
// SINGLE barrier/iter: wait vmcnt(0) (only K[t],V[t] outstanding) + barrier at loop top; the
// same barrier proves all waves finished last iter's reads of buf^1 -> safe to overwrite.
__global__ __launch_bounds__(256, 4) void attn_k(const short* __restrict__ qk, const short* __restrict__ v,
                                                 short* __restrict__ OPB, float* __restrict__ Lb) {
  __shared__ short ks2[2][64 * 64];   // K tile [s][d], swizzled, double-buffered (16KB)
  __shared__ short vs2[2][64 * 64];   // V tile [d][s], swizzled, double-buffered (16KB)
  __shared__ short pbuf[4][32 * 64];  // per-wave P [t][s], swizzled              (16KB)
  const int bid = blockIdx.x;                       // 0..1023
  const int swz = (bid & 7) * 128 + (bid >> 3);     // XCD-contiguous chunks of 128
  const int qt = swz & 15;                          // fastest within chunk
  const int grp = swz >> 4;                         // (bh,seg) group, 8 per XCD
  const int bh = grp & 15, seg = grp >> 4;
  const int b = bh >> 3, h = bh & 7;
  const int lane = threadIdx.x & 63, wid = threadIdx.x >> 6;
  const int g = lane >> 4, c = lane & 15;
  const int q0 = qt * 128 + wid * 32;
  short* pl = pbuf[wid];

  const short* qp = qk + (size_t)(b * 2048 + q0) * 1024 + h * 64;
  const short* kb = qk + (size_t)(b * 2048) * 1024 + 512 + h * 64;
  const short* vb = v + (size_t)(h * 64) * 4096 + b * 2048;

  // Q as B-operand frags (rows t, once per block)
  short8 qf[2][2];
#pragma unroll
  for (int nj = 0; nj < 2; ++nj)
#pragma unroll
    for (int kk = 0; kk < 2; ++kk)
      qf[nj][kk] = *(const short8*)(qp + (size_t)(nj * 16 + c) * 1024 + kk * 32 + g * 8);

  // staging geometry: row-of-8 blocks, XOR-pre-swizzled source column (16B granules)
  const int sr = lane >> 3;                 // 0..7 (== row&7)
  const int scol = ((lane & 7) ^ sr) * 8;   // shorts

  const int kvbeg = seg * 512;
  // prologue: issue K[0], V[0] -> buf 0 (4 loads outstanding)
#pragma unroll
  for (int q = 0; q < 2; ++q) {
    const int blk = wid * 2 + q;
    const int row = blk * 8 + sr;
    gload_lds16(kb + (size_t)(kvbeg + row) * 1024 + scol, &ks2[0][blk * 512]);
    gload_lds16(vb + (size_t)row * 4096 + kvbeg + scol, &vs2[0][blk * 512]);
  }

  f32x4 oacc[4][2] = {};      // [dj][o]: O^T rows d=dj*16+g*4+r, col t=o*16+c
  float lpart[2] = {0.f, 0.f};
  const float LOG2E = 1.44269504088896f;
  const float M2 = 5.770780163555852f;  // 4*log2(e): fixed softmax shift (exact)

  for (int it8 = 0; it8 < 8; ++it8) {
    const int bufi = it8 & 1;

    // (1) K[t],V[t] ready (only outstanding loads) + all waves done reading buf^1
    asm volatile("s_waitcnt vmcnt(0)" ::: "memory");
    __builtin_amdgcn_s_barrier();

    // (2) issue K[t+1], V[t+1] -> buf^1 (wrapped at t=7: count-invariant, target never read)
    {
      const int kvn = kvbeg + ((it8 + 1) & 7) * 64;
#pragma unroll
      for (int q = 0; q < 2; ++q) {
        const int blk = wid * 2 + q;
        const int row = blk * 8 + sr;
        gload_lds16(kb + (size_t)(kvn + row) * 1024 + scol, &ks2[bufi ^ 1][blk * 512]);
        gload_lds16(vb + (size_t)row * 4096 + kvn + scol, &vs2[bufi ^ 1][blk * 512]);
      }
    }

    // (3) QK^T swapped: S^T[mi][nj], rows s=mi*16+g*4+r, col t=nj*16+c
    f32x4 st[4][2] = {};
    __builtin_amdgcn_s_setprio(1);
#pragma unroll
    for (int kk = 0; kk < 2; ++kk) {
      short8 kf[4];
#pragma unroll
      for (int mi = 0; mi < 4; ++mi) {
        const int row = mi * 16 + c;
        kf[mi] = *(const short8*)(&ks2[bufi][(row * 64 + kk * 32 + g * 8) ^ ((row & 7) << 3)]);
      }
#pragma unroll
      for (int mi = 0; mi < 4; ++mi)
#pragma unroll
        for (int nj = 0; nj < 2; ++nj)
          st[mi][nj] = __builtin_amdgcn_mfma_f32_16x16x32_bf16(kf[mi], qf[nj][kk], st[mi][nj], 0, 0, 0);
    }
    __builtin_amdgcn_s_setprio(0);

    // (4) P = exp2(s*LOG2E - M2) = e^(s-4); pack bf16; swizzled 8B stores to pbuf[t][s]
#pragma unroll
    for (int mi = 0; mi < 4; ++mi)
#pragma unroll
      for (int nj = 0; nj < 2; ++nj) {
        const float p0 = __builtin_amdgcn_exp2f(__builtin_fmaf(st[mi][nj][0], LOG2E, -M2));
        const float p1 = __builtin_amdgcn_exp2f(__builtin_fmaf(st[mi][nj][1], LOG2E, -M2));
        const float p2 = __builtin_amdgcn_exp2f(__builtin_fmaf(st[mi][nj][2], LOG2E, -M2));
        const float p3 = __builtin_amdgcn_exp2f(__builtin_fmaf(st[mi][nj][3], LOG2E, -M2));
        lpart[nj] += (p0 + p1) + (p2 + p3);
        const unsigned w0 = pk_bf16(p0, p1);
        const unsigned w1 = pk_bf16(p2, p3);
        const int t = nj * 16 + c;
        *(int2v*)(pl + ((t * 64 + mi * 16 + g * 4) ^ ((t & 7) << 3))) = (int2v){(int)w0, (int)w1};
      }

    // (5) PV swapped: O^T[dj][o] += V^T-frag(dj) x P-frag(o)
    __builtin_amdgcn_s_setprio(1);
#pragma unroll
    for (int kk = 0; kk < 2; ++kk) {
      short8 vf[4], pa[2];
#pragma unroll
      for (int dj = 0; dj < 4; ++dj) {
        const int row = dj * 16 + c;
        vf[dj] = *(const short8*)(&vs2[bufi][(row * 64 + kk * 32 + g * 8) ^ ((row & 7) << 3)]);
      }
#pragma unroll
      for (int o = 0; o < 2; ++o) {
        const int row = o * 16 + c;
        pa[o] = *(const short8*)(pl + ((row * 64 + kk * 32 + g * 8) ^ ((row & 7) << 3)));
      }
#pragma unroll
      for (int dj = 0; dj < 4; ++dj)
#pragma unroll
        for (int o = 0; o < 2; ++o)
          oacc[dj][o] = __builtin_amdgcn_mfma_f32_16x16x32_bf16(vf[dj], pa[o], oacc[dj][o], 0, 0, 0);
    }
    __builtin_amdgcn_s_setprio(0);
    // no end-of-iter barrier: next iter's top barrier orders buf reuse
  }

  // epilogue: row sums (reduce over g-groups once), unnormalized O^T -> OPB (bf16, 8B stores)
  float lrow[2];
#pragma unroll
  for (int nj = 0; nj < 2; ++nj) {
    float a = lpart[nj];
    a += __shfl_xor(a, 16);
    a += __shfl_xor(a, 32);
    lrow[nj] = a;
  }
  const size_t rbase = (size_t)seg * 32768 + (size_t)bh * 2048 + q0;
#pragma unroll
  for (int o = 0; o < 2; ++o) {
    const int t = o * 16 + c;
#pragma unroll
    for (int dj = 0; dj < 4; ++dj) {
      short4v w;
#pragma unroll
      for (int r = 0; r < 4; ++r) w[r] = f2bf(oacc[dj][o][r]);
      *(short4v*)(OPB + (rbase + t) * 64 + dj * 16 + g * 4) = w;
    }
    if (g == 0) Lb[rbase + t] = lrow[o];
  }
  // drain wrapped prefetch DMAs before wave exit (LDS dealloc hazard)
  asm volatile("s_waitcnt vmcnt(0)" ::: "memory");
}

// ---------------- merge: sum 4 bf16 kv-segment partials -> OB bf16 [(b*2048+t)*512 + h*64+d] ----
__global__ __launch_bounds__(256) void merge_k(const short* __restrict__ OPB, const float* __restrict__ Lb,
                                               short* __restrict__ o) {
  const int gid = blockIdx.x * 256 + threadIdx.x;  // 131072 threads
  const int row = gid >> 2;                        // bh*2048 + s
  const int dg = (gid & 3) * 16;
  float L = 0.f;
#pragma unroll
  for (int s = 0; s < 4; ++s) L += Lb[s * 32768 + row];
  const float rinv = 1.f / L;
  float acc[16];
#pragma unroll
  for (int j = 0; j < 16; ++j) acc[j] = 0.f;
#pragma unroll
  for (int s = 0; s < 4; ++s) {
#pragma unroll
    for (int q = 0; q < 2; ++q) {
      const short8 vv = *(const short8*)(OPB + ((size_t)s * 32768 + row) * 64 + dg + q * 8);
#pragma unroll
      for (int r = 0; r < 8; ++r) acc[q * 8 + r] += bf2f(vv[r]);
    }
  }
  const int bh = row >> 11, srow = row & 2047;
  const int b = bh >> 3, h = bh & 7;
  short8 st[2];
#pragma unroll
  for (int j = 0; j < 16; ++j) st[j >> 3][j & 7] = f2bf(acc[j] * rinv);
  short* dst = o + (size_t)(b * 2048 + srow) * 512 + h * 64 + dg;
  *(short8*)dst = st[0];
  *(short8*)(dst + 8) = st[1];
}

// ---------------- launcher ----------------
extern "C" void kernel_launch(void* const* d_in, const int* in_sizes, int n_in,
                              void* d_out, int out_size, void* d_ws, size_t ws_size,
                              hipStream_t stream) {
  const float* x  = (const float*)d_in[0];
  const float* wq = (const float*)d_in[1];
  const float* bq = (const float*)d_in[2];
  const float* wk = (const float*)d_in[3];
  const float* bk = (const float*)d_in[4];
  const float* wv = (const float*)d_in[5];
  const float* bv = (const float*)d_in[6];
  const float* wo = (const float*)d_in[7];
  const float* bo = (const float*)d_in[8];

  short* XT  = (short*)d_ws;                       // 4096*512 bf16
  short* WQKV = XT + (size_t)4096 * 512;           // 1536*512 (wq|wk|wv)
  short* WO  = WQKV + (size_t)1536 * 512;          // 512*512
  short* QKB = WO + (size_t)512 * 512;             // 4096*1024
  short* VB  = QKB + (size_t)4096 * 1024;          // 512*4096
  short* OB  = VB + (size_t)512 * 4096;            // 4096*512
  short* OPB = OB + (size_t)4096 * 512;            // 4*32768*64 bf16 partial O
  float* Lb  = (float*)(OPB + (size_t)4 * 32768 * 64);  // 4*32768 f32

  prep_k<<<dim3(3072), 256, 0, stream>>>(x, XT, wq, wk, wv, wo, WQKV);
  gemm_bt_k<0><<<dim3(384), 256, 0, stream>>>(WQKV, XT, (void*)QKB, VB, bq, bk, bv);
  attn_k<<<dim3(1024), 256, 0, stream>>>(QKB, VB, OPB, Lb);
  merge_k<<<dim3(512), 256, 0, stream>>>(OPB, Lb, OB);
  gemm_bt_k<2><<<dim3(256), 256, 0, stream>>>(OB, WO, d_out, nullptr, bo, nullptr, nullptr);
}

// Round 14
// 70.418 us; speedup vs baseline: 1.2085x; 1.0367x over previous
//
#include <hip/hip_runtime.h>
#include <hip/hip_bf16.h>

// MHSA: x(2,512,2048) f32, 8 heads x 64. All heavy math in bf16 MFMA 16x16x32.
// Pipeline: prep(xpose+wconv) -> gemm_bt<0>(fused QKV) -> attn(kv-split 4) -> merge -> gemm_bt<2>(out)
// attn: 8-wave blocks (256-row Q-tile), grid 512 = exactly 2 blocks/CU (64KB LDS), zero tail;
//       XCD-swizzled; swapped QK^T/PV; fixed-shift softmax (exact); K+V double-buffered via
//       global_load_lds; SINGLE barrier/iter (wait-then-issue).

typedef __attribute__((ext_vector_type(8))) short short8;   // 8 bf16 = 4 VGPR (MFMA A/B frag)
typedef __attribute__((ext_vector_type(4))) short short4v;  // 4 bf16 (8B store)
typedef __attribute__((ext_vector_type(4))) float f32x4;    // MFMA C/D frag
typedef __attribute__((ext_vector_type(2))) int int2v;      // 8B LDS store

#define DEV static __device__ __forceinline__

DEV short f2bf(float f) {  // fp32 -> bf16 RNE
  union { float f; unsigned u; } v; v.f = f;
  unsigned r = (v.u + 0x7FFFu + ((v.u >> 16) & 1u)) >> 16;
  return (short)r;
}

DEV float bf2f(short s) {  // bf16 -> fp32 (exact)
  union { unsigned u; float f; } v;
  v.u = ((unsigned)(unsigned short)s) << 16;
  return v.f;
}

DEV unsigned pk_bf16(float lo, float hi) {  // compiler emits v_cvt_pk_bf16_f32 (RNE)
  union { __hip_bfloat162 h; unsigned u; } cv;
  cv.h = __float22bfloat162_rn(float2{lo, hi});
  return cv.u;
}

DEV void gload_lds16(const void* g, void* l) {
  // wave-uniform LDS base; HW writes lane*16B
  __builtin_amdgcn_global_load_lds((const __attribute__((address_space(1))) void*)g,
                                   (__attribute__((address_space(3))) void*)l, 16, 0, 0);
}

// ---------------- prep: [bid<2048] x (B,512,2048) f32 -> XT[(b*2048+s)][512] bf16
//                  [bid>=2048] weights f32 -> bf16 concat [wq|wk|wv|wo] ----------------
__global__ __launch_bounds__(256) void prep_k(const float* __restrict__ x, short* __restrict__ xt,
                                              const float* __restrict__ wq, const float* __restrict__ wk,
                                              const float* __restrict__ wv, const float* __restrict__ wo,
                                              short* __restrict__ wdst) {
  __shared__ float tile[32][33];
  const int bid = blockIdx.x;
  if (bid < 2048) {
    const int b = bid >> 10, rest = bid & 1023;
    const int s0 = (rest & 63) * 32, c0 = (rest >> 6) * 32;
    const int tl = threadIdx.x & 31, tr = threadIdx.x >> 5;  // tr 0..7
    const float* src = x + ((size_t)b * 512 + c0) * 2048 + s0;
#pragma unroll
    for (int i = 0; i < 4; ++i)
      tile[tr + i * 8][tl] = src[(size_t)(tr + i * 8) * 2048 + tl];  // tile[c][s]
    __syncthreads();
    short* dst = xt + ((size_t)b * 2048 + s0) * 512 + c0;
#pragma unroll
    for (int i = 0; i < 4; ++i) {
      const int s = tr + i * 8;
      dst[(size_t)s * 512 + tl] = f2bf(tile[tl][s]);
    }
  } else {
    const int idx = (bid - 2048) * 256 + threadIdx.x;  // 262144 threads, 4 elems each
    const int m = idx >> 16;
    const int base = (idx & 65535) * 4;
    const float* src = (m == 0) ? wq : (m == 1) ? wk : (m == 2) ? wv : wo;
    const f32x4 v = *(const f32x4*)(src + base);
    short4v o;
#pragma unroll
    for (int r = 0; r < 4; ++r) o[r] = f2bf(v[r]);
    *(short4v*)(wdst + (size_t)idx * 4) = o;
  }
}

// ---------------- gemm_bt: D[i][j] = sum_k A[i][k]*B[j][k], K=512, BK=64 ----
// MODE 0 (fused QKV): tile 128x128, A=Wqkv[1536][512], B=XT[4096][512], grid 384 (XCD-swizzled).
//   i<512: Q -> QKB[j*1024+i] scaled 1/8 +bq | 512..1023: K -> QKB[j*1024+i] +bk
//   i>=1024: V -> VB[(i-1024)*4096+j] +bv (transposed store)
// MODE 2: tile 64x128 (256 blocks, full CU coverage), A=OB[4096][512], B=Wo[512][512]
//   -> out f32 (B,512,S) (+bias0(j)), i=(b,t)
template <int MODE>
__global__ __launch_bounds__(256) void gemm_bt_k(const short* __restrict__ A, const short* __restrict__ B,
                                                 void* __restrict__ out, short* __restrict__ out2,
                                                 const float* __restrict__ bias0,
                                                 const float* __restrict__ bias1,
                                                 const float* __restrict__ bias2) {
  constexpr int TM = (MODE == 0) ? 128 : 64;    // M-tile
  constexpr int MI = TM / 32;                   // acc rows per wave (4 or 2)
  constexpr int ABLK = TM / 32;                 // A staging blocks per wave (4 or 2)
  constexpr int NI = (MODE == 0) ? 12 : 64;     // M-tiles in grid
  constexpr int CHUNK = (MODE == 0) ? 48 : 32;  // gridDim/8, grid % 8 == 0
  __shared__ short As[TM * 64];
  __shared__ short Bs[128 * 64];
  const int bx0 = blockIdx.x;
  const int bx = (bx0 & 7) * CHUNK + (bx0 >> 3);  // XCD-contiguous chunks
  const int it = bx % NI, jt = bx / NI;
  const int tid = threadIdx.x;
  const int lane = tid & 63, wid = tid >> 6;
  const int wi = wid & 1, wj = wid >> 1;
  const int g = lane >> 4, c = lane & 15;

  f32x4 acc[MI][4] = {};

  for (int k0 = 0; k0 < 512; k0 += 64) {
#pragma unroll
    for (int q = 0; q < ABLK; ++q) {
      const int blk = wid * ABLK + q;           // TM/8 blocks of 8 rows
      const int row = blk * 8 + (lane >> 3);
      const int ks = ((lane & 7) ^ (row & 7)) * 8;
      gload_lds16(A + (size_t)(it * TM + row) * 512 + k0 + ks, As + blk * 512);
    }
#pragma unroll
    for (int q = 0; q < 4; ++q) {
      const int blk = wid * 4 + q;              // 16 blocks of 8 rows
      const int row = blk * 8 + (lane >> 3);
      const int ks = ((lane & 7) ^ (row & 7)) * 8;
      gload_lds16(B + (size_t)(jt * 128 + row) * 512 + k0 + ks, Bs + blk * 512);
    }
    __syncthreads();
#pragma unroll
    for (int kk = 0; kk < 2; ++kk) {
      short8 af[MI], bfv[4];
#pragma unroll
      for (int mi = 0; mi < MI; ++mi) {
        const int row = wi * (TM / 2) + mi * 16 + c;
        af[mi] = *(const short8*)(As + ((row * 64 + kk * 32 + g * 8) ^ ((row & 7) << 3)));
      }
#pragma unroll
      for (int nj = 0; nj < 4; ++nj) {
        const int row = wj * 64 + nj * 16 + c;
        bfv[nj] = *(const short8*)(Bs + ((row * 64 + kk * 32 + g * 8) ^ ((row & 7) << 3)));
      }
#pragma unroll
      for (int mi = 0; mi < MI; ++mi)
#pragma unroll
        for (int nj = 0; nj < 4; ++nj)
          acc[mi][nj] = __builtin_amdgcn_mfma_f32_16x16x32_bf16(af[mi], bfv[nj], acc[mi][nj], 0, 0, 0);
    }
    __syncthreads();
  }

  // epilogue: D[i][j], lane holds rows i0+g*4+r at col j (4 consecutive i -> vector store)
  if constexpr (MODE == 0) {
    short* ob = (short*)out;
#pragma unroll
    for (int mi = 0; mi < MI; ++mi) {
      const int i0 = it * 128 + wi * 64 + mi * 16 + g * 4;  // wave-uniform range per mi
      if (i0 < 1024) {  // Q or K -> QKB[j*1024 + i]
        const bool isQ = i0 < 512;
        const float scale = isQ ? 0.125f : 1.0f;  // fold 1/sqrt(hd)=1/8 into Q
        const float* bp = isQ ? bias0 : bias1;
        const int boff = isQ ? 0 : 512;
        float b4[4];
#pragma unroll
        for (int r = 0; r < 4; ++r) b4[r] = bp[i0 + r - boff];
#pragma unroll
        for (int nj = 0; nj < 4; ++nj) {
          const int j = jt * 128 + wj * 64 + nj * 16 + c;
          short4v st;
#pragma unroll
          for (int r = 0; r < 4; ++r) st[r] = f2bf((acc[mi][nj][r] + b4[r]) * scale);
          *(short4v*)(ob + (size_t)j * 1024 + i0) = st;
        }
      } else {  // V -> VB[(i-1024)*4096 + j] (transposed scalar stores, 16-lane contiguous)
        float b4[4];
#pragma unroll
        for (int r = 0; r < 4; ++r) b4[r] = bias2[i0 + r - 1024];
#pragma unroll
        for (int nj = 0; nj < 4; ++nj) {
          const int j = jt * 128 + wj * 64 + nj * 16 + c;
#pragma unroll
          for (int r = 0; r < 4; ++r)
            out2[(size_t)(i0 + r - 1024) * 4096 + j] = f2bf(acc[mi][nj][r] + b4[r]);
        }
      }
    }
  } else {
    float* ob = (float*)out;
#pragma unroll
    for (int mi = 0; mi < MI; ++mi) {
      const int i0 = it * 64 + wi * 32 + mi * 16 + g * 4;
      const int bb = i0 >> 11, t = i0 & 2047;
#pragma unroll
      for (int nj = 0; nj < 4; ++nj) {
        const int j = jt * 128 + wj * 64 + nj * 16 + c;
        const float bj = bias0[j];
        f32x4 st;
#pragma unroll
        for (int r = 0; r < 4; ++r) st[r] = acc[mi][nj][r] + bj;
        *(f32x4*)(ob + ((size_t)(bb * 512 + j)) * 2048 + t) = st;
      }
    }
  }
}

// ---------------- attention (kv-split): per (b,h,seg), flash over 8 kv tiles of 64 ----
// Grid 1D 512, 8 waves/block (Q-tile 256 rows), XCD-swizzled: 8 qt-blocks sharing a (bh,seg)
// K/V slice land on ONE XCD; exactly 2 blocks/CU (64KB LDS), zero tail.
// Swapped QK^T/PV; fixed-shift softmax P=e^(s-4) (exact). SINGLE barrier/iter: vmcnt(0)
// (only own K[t],V[t] outstanding) + barrier at loop top; same barrier frees buf^1.
__global__ __launch_bounds__(512, 4) void attn_k(const short* __restrict__ qk, const short* __restrict__ v,
                                                 short* __restrict__ OPB, float* __restrict__ Lb) {
  __shared__ short ks2[2][64 * 64];   // K tile [s][d], swizzled, double-buffered (16KB)
  __shared__ short vs2[2][64 * 64];   // V tile [d][s], swizzled, double-buffered (16KB)
  __shared__ short pbuf[8][32 * 64];  // per-wave P [t][s], swizzled              (32KB)
  const int bid = blockIdx.x;                       // 0..511
  const int swz = (bid & 7) * 64 + (bid >> 3);      // XCD-contiguous chunks of 64
  const int qt = swz & 7;                           // fastest within chunk
  const int grp = swz >> 3;                         // (bh,seg) group, 8 per XCD
  const int bh = grp & 15, seg = grp >> 4;
  const int b = bh >> 3, h = bh & 7;
  const int lane = threadIdx.x & 63, wid = threadIdx.x >> 6;  // wid 0..7
  const int g = lane >> 4, c = lane & 15;
  const int q0 = qt * 256 + wid * 32;
  short* pl = pbuf[wid];

  const short* qp = qk + (size_t)(b * 2048 + q0) * 1024 + h * 64;
  const short* kb = qk + (size_t)(b * 2048) * 1024 + 512 + h * 64;
  const short* vb = v + (size_t)(h * 64) * 4096 + b * 2048;

  // Q as B-operand frags (rows t, once per block)
  short8 qf[2][2];
#pragma unroll
  for (int nj = 0; nj < 2; ++nj)
#pragma unroll
    for (int kk = 0; kk < 2; ++kk)
      qf[nj][kk] = *(const short8*)(qp + (size_t)(nj * 16 + c) * 1024 + kk * 32 + g * 8);

  // staging geometry: 8 waves x 1 block of 8 rows each, XOR-pre-swizzled source column
  const int sr = lane >> 3;                 // 0..7 (== row&7)
  const int scol = ((lane & 7) ^ sr) * 8;   // shorts
  const int srow = wid * 8 + sr;            // this wave's staging rows

  const int kvbeg = seg * 512;
  // prologue: issue K[0], V[0] -> buf 0 (2 loads/wave outstanding)
  gload_lds16(kb + (size_t)(kvbeg + srow) * 1024 + scol, &ks2[0][wid * 512]);
  gload_lds16(vb + (size_t)srow * 4096 + kvbeg + scol, &vs2[0][wid * 512]);

  f32x4 oacc[4][2] = {};      // [dj][o]: O^T rows d=dj*16+g*4+r, col t=o*16+c
  float lpart[2] = {0.f, 0.f};
  const float LOG2E = 1.44269504088896f;
  const float M2 = 5.770780163555852f;  // 4*log2(e): fixed softmax shift (exact)

  for (int it8 = 0; it8 < 8; ++it8) {
    const int bufi = it8 & 1;

    // (1) K[t],V[t] ready (only own outstanding loads) + all waves done reading buf^1
    asm volatile("s_waitcnt vmcnt(0)" ::: "memory");
    __builtin_amdgcn_s_barrier();

    // (2) issue K[t+1], V[t+1] -> buf^1 (wrapped at t=7: count-invariant, target never read)
    {
      const int kvn = kvbeg + ((it8 + 1) & 7) * 64;
      gload_lds16(kb + (size_t)(kvn + srow) * 1024 + scol, &ks2[bufi ^ 1][wid * 512]);
      gload_lds16(vb + (size_t)srow * 4096 + kvn + scol, &vs2[bufi ^ 1][wid * 512]);
    }

    // (3) QK^T swapped: S^T[mi][nj], rows s=mi*16+g*4+r, col t=nj*16+c
    f32x4 st[4][2] = {};
    __builtin_amdgcn_s_setprio(1);
#pragma unroll
    for (int kk = 0; kk < 2; ++kk) {
      short8 kf[4];
#pragma unroll
      for (int mi = 0; mi < 4; ++mi) {
        const int row = mi * 16 + c;
        kf[mi] = *(const short8*)(&ks2[bufi][(row * 64 + kk * 32 + g * 8) ^ ((row & 7) << 3)]);
      }
#pragma unroll
      for (int mi = 0; mi < 4; ++mi)
#pragma unroll
        for (int nj = 0; nj < 2; ++nj)
          st[mi][nj] = __builtin_amdgcn_mfma_f32_16x16x32_bf16(kf[mi], qf[nj][kk], st[mi][nj], 0, 0, 0);
    }
    __builtin_amdgcn_s_setprio(0);

    // (4) P = exp2(s*LOG2E - M2) = e^(s-4); pack bf16; swizzled 8B stores to pbuf[t][s]
#pragma unroll
    for (int mi = 0; mi < 4; ++mi)
#pragma unroll
      for (int nj = 0; nj < 2; ++nj) {
        const float p0 = __builtin_amdgcn_exp2f(__builtin_fmaf(st[mi][nj][0], LOG2E, -M2));
        const float p1 = __builtin_amdgcn_exp2f(__builtin_fmaf(st[mi][nj][1], LOG2E, -M2));
        const float p2 = __builtin_amdgcn_exp2f(__builtin_fmaf(st[mi][nj][2], LOG2E, -M2));
        const float p3 = __builtin_amdgcn_exp2f(__builtin_fmaf(st[mi][nj][3], LOG2E, -M2));
        lpart[nj] += (p0 + p1) + (p2 + p3);
        const unsigned w0 = pk_bf16(p0, p1);
        const unsigned w1 = pk_bf16(p2, p3);
        const int t = nj * 16 + c;
        *(int2v*)(pl + ((t * 64 + mi * 16 + g * 4) ^ ((t & 7) << 3))) = (int2v){(int)w0, (int)w1};
      }

    // (5) PV swapped: O^T[dj][o] += V^T-frag(dj) x P-frag(o)
    __builtin_amdgcn_s_setprio(1);
#pragma unroll
    for (int kk = 0; kk < 2; ++kk) {
      short8 vf[4], pa[2];
#pragma unroll
      for (int dj = 0; dj < 4; ++dj) {
        const int row = dj * 16 + c;
        vf[dj] = *(const short8*)(&vs2[bufi][(row * 64 + kk * 32 + g * 8) ^ ((row & 7) << 3)]);
      }
#pragma unroll
      for (int o = 0; o < 2; ++o) {
        const int row = o * 16 + c;
        pa[o] = *(const short8*)(pl + ((row * 64 + kk * 32 + g * 8) ^ ((row & 7) << 3)));
      }
#pragma unroll
      for (int dj = 0; dj < 4; ++dj)
#pragma unroll
        for (int o = 0; o < 2; ++o)
          oacc[dj][o] = __builtin_amdgcn_mfma_f32_16x16x32_bf16(vf[dj], pa[o], oacc[dj][o], 0, 0, 0);
    }
    __builtin_amdgcn_s_setprio(0);
    // no end-of-iter barrier: next iter's top barrier orders buf reuse
  }

  // epilogue: row sums (reduce over g-groups once), unnormalized O^T -> OPB (bf16, 8B stores)
  float lrow[2];
#pragma unroll
  for (int nj = 0; nj < 2; ++nj) {
    float a = lpart[nj];
    a += __shfl_xor(a, 16);
    a += __shfl_xor(a, 32);
    lrow[nj] = a;
  }
  const size_t rbase = (size_t)seg * 32768 + (size_t)bh * 2048 + q0;
#pragma unroll
  for (int o = 0; o < 2; ++o) {
    const int t = o * 16 + c;
#pragma unroll
    for (int dj = 0; dj < 4; ++dj) {
      short4v w;
#pragma unroll
      for (int r = 0; r < 4; ++r) w[r] = f2bf(oacc[dj][o][r]);
      *(short4v*)(OPB + (rbase + t) * 64 + dj * 16 + g * 4) = w;
    }
    if (g == 0) Lb[rbase + t] = lrow[o];
  }
  // drain wrapped prefetch DMAs before wave exit (LDS dealloc hazard)
  asm volatile("s_waitcnt vmcnt(0)" ::: "memory");
}

// ---------------- merge: sum 4 bf16 kv-segment partials -> OB bf16 [(b*2048+t)*512 + h*64+d] ----
__global__ __launch_bounds__(256) void merge_k(const short* __restrict__ OPB, const float* __restrict__ Lb,
                                               short* __restrict__ o) {
  const int gid = blockIdx.x * 256 + threadIdx.x;  // 131072 threads
  const int row = gid >> 2;                        // bh*2048 + s
  const int dg = (gid & 3) * 16;
  float L = 0.f;
#pragma unroll
  for (int s = 0; s < 4; ++s) L += Lb[s * 32768 + row];
  const float rinv = 1.f / L;
  float acc[16];
#pragma unroll
  for (int j = 0; j < 16; ++j) acc[j] = 0.f;
#pragma unroll
  for (int s = 0; s < 4; ++s) {
#pragma unroll
    for (int q = 0; q < 2; ++q) {
      const short8 vv = *(const short8*)(OPB + ((size_t)s * 32768 + row) * 64 + dg + q * 8);
#pragma unroll
      for (int r = 0; r < 8; ++r) acc[q * 8 + r] += bf2f(vv[r]);
    }
  }
  const int bh = row >> 11, srow = row & 2047;
  const int b = bh >> 3, h = bh & 7;
  short8 st[2];
#pragma unroll
  for (int j = 0; j < 16; ++j) st[j >> 3][j & 7] = f2bf(acc[j] * rinv);
  short* dst = o + (size_t)(b * 2048 + srow) * 512 + h * 64 + dg;
  *(short8*)dst = st[0];
  *(short8*)(dst + 8) = st[1];
}

// ---------------- launcher ----------------
extern "C" void kernel_launch(void* const* d_in, const int* in_sizes, int n_in,
                              void* d_out, int out_size, void* d_ws, size_t ws_size,
                              hipStream_t stream) {
  const float* x  = (const float*)d_in[0];
  const float* wq = (const float*)d_in[1];
  const float* bq = (const float*)d_in[2];
  const float* wk = (const float*)d_in[3];
  const float* bk = (const float*)d_in[4];
  const float* wv = (const float*)d_in[5];
  const float* bv = (const float*)d_in[6];
  const float* wo = (const float*)d_in[7];
  const float* bo = (const float*)d_in[8];

  short* XT  = (short*)d_ws;                       // 4096*512 bf16
  short* WQKV = XT + (size_t)4096 * 512;           // 1536*512 (wq|wk|wv)
  short* WO  = WQKV + (size_t)1536 * 512;          // 512*512
  short* QKB = WO + (size_t)512 * 512;             // 4096*1024
  short* VB  = QKB + (size_t)4096 * 1024;          // 512*4096
  short* OB  = VB + (size_t)512 * 4096;            // 4096*512
  short* OPB = OB + (size_t)4096 * 512;            // 4*32768*64 bf16 partial O
  float* Lb  = (float*)(OPB + (size_t)4 * 32768 * 64);  // 4*32768 f32

  prep_k<<<dim3(3072), 256, 0, stream>>>(x, XT, wq, wk, wv, wo, WQKV);
  gemm_bt_k<0><<<dim3(384), 256, 0, stream>>>(WQKV, XT, (void*)QKB, VB, bq, bk, bv);
  attn_k<<<dim3(512), 512, 0, stream>>>(QKB, VB, OPB, Lb);
  merge_k<<<dim3(512), 256, 0, stream>>>(OPB, Lb, OB);
  gemm_bt_k<2><<<dim3(256), 256, 0, stream>>>(OB, WO, d_out, nullptr, bo, nullptr, nullptr);
}

// Round 15
// 65.979 us; speedup vs baseline: 1.2898x; 1.0673x over previous
//
#include <hip/hip_runtime.h>
#include <hip/hip_bf16.h>

// MHSA: x(2,512,2048) f32, 8 heads x 64. All heavy math in bf16 MFMA 16x16x32.
// Pipeline: prep(xpose+wconv) -> gemm_bt<0>(fused QKV) -> attn(kv-split 4) -> merge -> gemm_bt<2>(out)
// attn: 8-wave blocks (256-row Q-tile), grid 512 = exactly 2 blocks/CU (64KB LDS), zero tail;
//       XCD-swizzled; swapped QK^T/PV; fixed-shift softmax (exact); K+V double-buffered via
//       global_load_lds; SINGLE barrier/iter (wait-then-issue).
// gemm0: 64x128 tiles -> grid 768 = exactly 3 blocks/CU (zero tail). gemm2: 64x128, grid 256.

typedef __attribute__((ext_vector_type(8))) short short8;   // 8 bf16 = 4 VGPR (MFMA A/B frag)
typedef __attribute__((ext_vector_type(4))) short short4v;  // 4 bf16 (8B store)
typedef __attribute__((ext_vector_type(4))) float f32x4;    // MFMA C/D frag
typedef __attribute__((ext_vector_type(2))) int int2v;      // 8B LDS store

#define DEV static __device__ __forceinline__

DEV short f2bf(float f) {  // fp32 -> bf16 RNE
  union { float f; unsigned u; } v; v.f = f;
  unsigned r = (v.u + 0x7FFFu + ((v.u >> 16) & 1u)) >> 16;
  return (short)r;
}

DEV float bf2f(short s) {  // bf16 -> fp32 (exact)
  union { unsigned u; float f; } v;
  v.u = ((unsigned)(unsigned short)s) << 16;
  return v.f;
}

DEV unsigned pk_bf16(float lo, float hi) {  // compiler emits v_cvt_pk_bf16_f32 (RNE)
  union { __hip_bfloat162 h; unsigned u; } cv;
  cv.h = __float22bfloat162_rn(float2{lo, hi});
  return cv.u;
}

DEV void gload_lds16(const void* g, void* l) {
  // wave-uniform LDS base; HW writes lane*16B
  __builtin_amdgcn_global_load_lds((const __attribute__((address_space(1))) void*)g,
                                   (__attribute__((address_space(3))) void*)l, 16, 0, 0);
}

// ---------------- prep: [bid<2048] x (B,512,2048) f32 -> XT[(b*2048+s)][512] bf16
//                  [bid>=2048] weights f32 -> bf16 concat [wq|wk|wv|wo] ----------------
__global__ __launch_bounds__(256) void prep_k(const float* __restrict__ x, short* __restrict__ xt,
                                              const float* __restrict__ wq, const float* __restrict__ wk,
                                              const float* __restrict__ wv, const float* __restrict__ wo,
                                              short* __restrict__ wdst) {
  __shared__ float tile[32][33];
  const int bid = blockIdx.x;
  if (bid < 2048) {
    const int b = bid >> 10, rest = bid & 1023;
    const int s0 = (rest & 63) * 32, c0 = (rest >> 6) * 32;
    const int tl = threadIdx.x & 31, tr = threadIdx.x >> 5;  // tr 0..7
    const float* src = x + ((size_t)b * 512 + c0) * 2048 + s0;
#pragma unroll
    for (int i = 0; i < 4; ++i)
      tile[tr + i * 8][tl] = src[(size_t)(tr + i * 8) * 2048 + tl];  // tile[c][s]
    __syncthreads();
    short* dst = xt + ((size_t)b * 2048 + s0) * 512 + c0;
#pragma unroll
    for (int i = 0; i < 4; ++i) {
      const int s = tr + i * 8;
      dst[(size_t)s * 512 + tl] = f2bf(tile[tl][s]);
    }
  } else {
    const int idx = (bid - 2048) * 256 + threadIdx.x;  // 262144 threads, 4 elems each
    const int m = idx >> 16;
    const int base = (idx & 65535) * 4;
    const float* src = (m == 0) ? wq : (m == 1) ? wk : (m == 2) ? wv : wo;
    const f32x4 v = *(const f32x4*)(src + base);
    short4v o;
#pragma unroll
    for (int r = 0; r < 4; ++r) o[r] = f2bf(v[r]);
    *(short4v*)(wdst + (size_t)idx * 4) = o;
  }
}

// ---------------- gemm_bt: D[i][j] = sum_k A[i][k]*B[j][k], K=512, BK=64, tile 64x128 ----
// MODE 0 (fused QKV): A=Wqkv[1536][512], B=XT[4096][512], NI=24, grid 768 = 3/CU zero-tail.
//   i<512: Q -> QKB[j*1024+i] scaled 1/8 +bq | 512..1023: K -> QKB[j*1024+i] +bk
//   i>=1024: V -> VB[(i-1024)*4096+j] +bv (transposed store)
// MODE 2: A=OB[4096][512], B=Wo[512][512], NI=64, grid 256 -> out f32 (B,512,S) (+bias0(j))
template <int MODE>
__global__ __launch_bounds__(256) void gemm_bt_k(const short* __restrict__ A, const short* __restrict__ B,
                                                 void* __restrict__ out, short* __restrict__ out2,
                                                 const float* __restrict__ bias0,
                                                 const float* __restrict__ bias1,
                                                 const float* __restrict__ bias2) {
  constexpr int NI = (MODE == 0) ? 24 : 64;     // M-tiles in grid
  constexpr int CHUNK = (MODE == 0) ? 96 : 32;  // gridDim/8, grid % 8 == 0
  __shared__ short As[64 * 64];
  __shared__ short Bs[128 * 64];
  const int bx0 = blockIdx.x;
  const int bx = (bx0 & 7) * CHUNK + (bx0 >> 3);  // XCD-contiguous chunks
  const int it = bx % NI, jt = bx / NI;
  const int tid = threadIdx.x;
  const int lane = tid & 63, wid = tid >> 6;
  const int wi = wid & 1, wj = wid >> 1;
  const int g = lane >> 4, c = lane & 15;

  f32x4 acc[2][4] = {};

  for (int k0 = 0; k0 < 512; k0 += 64) {
#pragma unroll
    for (int q = 0; q < 2; ++q) {
      const int blk = wid * 2 + q;              // 8 blocks of 8 rows
      const int row = blk * 8 + (lane >> 3);
      const int ks = ((lane & 7) ^ (row & 7)) * 8;
      gload_lds16(A + (size_t)(it * 64 + row) * 512 + k0 + ks, As + blk * 512);
    }
#pragma unroll
    for (int q = 0; q < 4; ++q) {
      const int blk = wid * 4 + q;              // 16 blocks of 8 rows
      const int row = blk * 8 + (lane >> 3);
      const int ks = ((lane & 7) ^ (row & 7)) * 8;
      gload_lds16(B + (size_t)(jt * 128 + row) * 512 + k0 + ks, Bs + blk * 512);
    }
    __syncthreads();
#pragma unroll
    for (int kk = 0; kk < 2; ++kk) {
      short8 af[2], bfv[4];
#pragma unroll
      for (int mi = 0; mi < 2; ++mi) {
        const int row = wi * 32 + mi * 16 + c;
        af[mi] = *(const short8*)(As + ((row * 64 + kk * 32 + g * 8) ^ ((row & 7) << 3)));
      }
#pragma unroll
      for (int nj = 0; nj < 4; ++nj) {
        const int row = wj * 64 + nj * 16 + c;
        bfv[nj] = *(const short8*)(Bs + ((row * 64 + kk * 32 + g * 8) ^ ((row & 7) << 3)));
      }
#pragma unroll
      for (int mi = 0; mi < 2; ++mi)
#pragma unroll
        for (int nj = 0; nj < 4; ++nj)
          acc[mi][nj] = __builtin_amdgcn_mfma_f32_16x16x32_bf16(af[mi], bfv[nj], acc[mi][nj], 0, 0, 0);
    }
    __syncthreads();
  }

  // epilogue: D[i][j], lane holds rows i0+g*4+r at col j (4 consecutive i -> vector store)
  if constexpr (MODE == 0) {
    short* ob = (short*)out;
#pragma unroll
    for (int mi = 0; mi < 2; ++mi) {
      const int i0 = it * 64 + wi * 32 + mi * 16 + g * 4;  // wave-uniform range per mi
      if (i0 < 1024) {  // Q or K -> QKB[j*1024 + i]
        const bool isQ = i0 < 512;
        const float scale = isQ ? 0.125f : 1.0f;  // fold 1/sqrt(hd)=1/8 into Q
        const float* bp = isQ ? bias0 : bias1;
        const int boff = isQ ? 0 : 512;
        float b4[4];
#pragma unroll
        for (int r = 0; r < 4; ++r) b4[r] = bp[i0 + r - boff];
#pragma unroll
        for (int nj = 0; nj < 4; ++nj) {
          const int j = jt * 128 + wj * 64 + nj * 16 + c;
          short4v st;
#pragma unroll
          for (int r = 0; r < 4; ++r) st[r] = f2bf((acc[mi][nj][r] + b4[r]) * scale);
          *(short4v*)(ob + (size_t)j * 1024 + i0) = st;
        }
      } else {  // V -> VB[(i-1024)*4096 + j] (transposed scalar stores, 16-lane contiguous)
        float b4[4];
#pragma unroll
        for (int r = 0; r < 4; ++r) b4[r] = bias2[i0 + r - 1024];
#pragma unroll
        for (int nj = 0; nj < 4; ++nj) {
          const int j = jt * 128 + wj * 64 + nj * 16 + c;
#pragma unroll
          for (int r = 0; r < 4; ++r)
            out2[(size_t)(i0 + r - 1024) * 4096 + j] = f2bf(acc[mi][nj][r] + b4[r]);
        }
      }
    }
  } else {
    float* ob = (float*)out;
#pragma unroll
    for (int mi = 0; mi < 2; ++mi) {
      const int i0 = it * 64 + wi * 32 + mi * 16 + g * 4;
      const int bb = i0 >> 11, t = i0 & 2047;
#pragma unroll
      for (int nj = 0; nj < 4; ++nj) {
        const int j = jt * 128 + wj * 64 + nj * 16 + c;
        const float bj = bias0[j];
        f32x4 st;
#pragma unroll
        for (int r = 0; r < 4; ++r) st[r] = acc[mi][nj][r] + bj;
        *(f32x4*)(ob + ((size_t)(bb * 512 + j)) * 2048 + t) = st;
      }
    }
  }
}

// ---------------- attention (kv-split): per (b,h,seg), flash over 8 kv tiles of 64 ----
// Grid 1D 512, 8 waves/block (Q-tile 256 rows), XCD-swizzled: 8 qt-blocks sharing a (bh,seg)
// K/V slice land on ONE XCD; exactly 2 blocks/CU (64KB LDS), zero tail.
// Swapped QK^T/PV; fixed-shift softmax P=e^(s-4) (exact). SINGLE barrier/iter: vmcnt(0)
// (only own K[t],V[t] outstanding) + barrier at loop top; same barrier frees buf^1.
__global__ __launch_bounds__(512, 4) void attn_k(const short* __restrict__ qk, const short* __restrict__ v,
                                                 short* __restrict__ OPB, float* __restrict__ Lb) {
  __shared__ short ks2[2][64 * 64];   // K tile [s][d], swizzled, double-buffered (16KB)
  __shared__ short vs2[2][64 * 64];   // V tile [d][s], swizzled, double-buffered (16KB)
  __shared__ short pbuf[8][32 * 64];  // per-wave P [t][s], swizzled              (32KB)
  const int bid = blockIdx.x;                       // 0..511
  const int swz = (bid & 7) * 64 + (bid >> 3);      // XCD-contiguous chunks of 64
  const int qt = swz & 7;                           // fastest within chunk
  const int grp = swz >> 3;                         // (bh,seg) group, 8 per XCD
  const int bh = grp & 15, seg = grp >> 4;
  const int b = bh >> 3, h = bh & 7;
  const int lane = threadIdx.x & 63, wid = threadIdx.x >> 6;  // wid 0..7
  const int g = lane >> 4, c = lane & 15;
  const int q0 = qt * 256 + wid * 32;
  short* pl = pbuf[wid];

  const short* qp = qk + (size_t)(b * 2048 + q0) * 1024 + h * 64;
  const short* kb = qk + (size_t)(b * 2048) * 1024 + 512 + h * 64;
  const short* vb = v + (size_t)(h * 64) * 4096 + b * 2048;

  // Q as B-operand frags (rows t, once per block)
  short8 qf[2][2];
#pragma unroll
  for (int nj = 0; nj < 2; ++nj)
#pragma unroll
    for (int kk = 0; kk < 2; ++kk)
      qf[nj][kk] = *(const short8*)(qp + (size_t)(nj * 16 + c) * 1024 + kk * 32 + g * 8);

  // staging geometry: 8 waves x 1 block of 8 rows each, XOR-pre-swizzled source column
  const int sr = lane >> 3;                 // 0..7 (== row&7)
  const int scol = ((lane & 7) ^ sr) * 8;   // shorts
  const int srow = wid * 8 + sr;            // this wave's staging rows

  const int kvbeg = seg * 512;
  // prologue: issue K[0], V[0] -> buf 0 (2 loads/wave outstanding)
  gload_lds16(kb + (size_t)(kvbeg + srow) * 1024 + scol, &ks2[0][wid * 512]);
  gload_lds16(vb + (size_t)srow * 4096 + kvbeg + scol, &vs2[0][wid * 512]);

  f32x4 oacc[4][2] = {};      // [dj][o]: O^T rows d=dj*16+g*4+r, col t=o*16+c
  float lpart[2] = {0.f, 0.f};
  const float LOG2E = 1.44269504088896f;
  const float M2 = 5.770780163555852f;  // 4*log2(e): fixed softmax shift (exact)

  for (int it8 = 0; it8 < 8; ++it8) {
    const int bufi = it8 & 1;

    // (1) K[t],V[t] ready (only own outstanding loads) + all waves done reading buf^1
    asm volatile("s_waitcnt vmcnt(0)" ::: "memory");
    __builtin_amdgcn_s_barrier();

    // (2) issue K[t+1], V[t+1] -> buf^1 (wrapped at t=7: count-invariant, target never read)
    {
      const int kvn = kvbeg + ((it8 + 1) & 7) * 64;
      gload_lds16(kb + (size_t)(kvn + srow) * 1024 + scol, &ks2[bufi ^ 1][wid * 512]);
      gload_lds16(vb + (size_t)srow * 4096 + kvn + scol, &vs2[bufi ^ 1][wid * 512]);
    }

    // (3) QK^T swapped: S^T[mi][nj], rows s=mi*16+g*4+r, col t=nj*16+c
    f32x4 st[4][2] = {};
    __builtin_amdgcn_s_setprio(1);
#pragma unroll
    for (int kk = 0; kk < 2; ++kk) {
      short8 kf[4];
#pragma unroll
      for (int mi = 0; mi < 4; ++mi) {
        const int row = mi * 16 + c;
        kf[mi] = *(const short8*)(&ks2[bufi][(row * 64 + kk * 32 + g * 8) ^ ((row & 7) << 3)]);
      }
#pragma unroll
      for (int mi = 0; mi < 4; ++mi)
#pragma unroll
        for (int nj = 0; nj < 2; ++nj)
          st[mi][nj] = __builtin_amdgcn_mfma_f32_16x16x32_bf16(kf[mi], qf[nj][kk], st[mi][nj], 0, 0, 0);
    }
    __builtin_amdgcn_s_setprio(0);

    // (4) P = exp2(s*LOG2E - M2) = e^(s-4); pack bf16; swizzled 8B stores to pbuf[t][s]
#pragma unroll
    for (int mi = 0; mi < 4; ++mi)
#pragma unroll
      for (int nj = 0; nj < 2; ++nj) {
        const float p0 = __builtin_amdgcn_exp2f(__builtin_fmaf(st[mi][nj][0], LOG2E, -M2));
        const float p1 = __builtin_amdgcn_exp2f(__builtin_fmaf(st[mi][nj][1], LOG2E, -M2));
        const float p2 = __builtin_amdgcn_exp2f(__builtin_fmaf(st[mi][nj][2], LOG2E, -M2));
        const float p3 = __builtin_amdgcn_exp2f(__builtin_fmaf(st[mi][nj][3], LOG2E, -M2));
        lpart[nj] += (p0 + p1) + (p2 + p3);
        const unsigned w0 = pk_bf16(p0, p1);
        const unsigned w1 = pk_bf16(p2, p3);
        const int t = nj * 16 + c;
        *(int2v*)(pl + ((t * 64 + mi * 16 + g * 4) ^ ((t & 7) << 3))) = (int2v){(int)w0, (int)w1};
      }

    // (5) PV swapped: O^T[dj][o] += V^T-frag(dj) x P-frag(o)
    __builtin_amdgcn_s_setprio(1);
#pragma unroll
    for (int kk = 0; kk < 2; ++kk) {
      short8 vf[4], pa[2];
#pragma unroll
      for (int dj = 0; dj < 4; ++dj) {
        const int row = dj * 16 + c;
        vf[dj] = *(const short8*)(&vs2[bufi][(row * 64 + kk * 32 + g * 8) ^ ((row & 7) << 3)]);
      }
#pragma unroll
      for (int o = 0; o < 2; ++o) {
        const int row = o * 16 + c;
        pa[o] = *(const short8*)(pl + ((row * 64 + kk * 32 + g * 8) ^ ((row & 7) << 3)));
      }
#pragma unroll
      for (int dj = 0; dj < 4; ++dj)
#pragma unroll
        for (int o = 0; o < 2; ++o)
          oacc[dj][o] = __builtin_amdgcn_mfma_f32_16x16x32_bf16(vf[dj], pa[o], oacc[dj][o], 0, 0, 0);
    }
    __builtin_amdgcn_s_setprio(0);
    // no end-of-iter barrier: next iter's top barrier orders buf reuse
  }

  // epilogue: row sums (reduce over g-groups once), unnormalized O^T -> OPB (bf16, 8B stores)
  float lrow[2];
#pragma unroll
  for (int nj = 0; nj < 2; ++nj) {
    float a = lpart[nj];
    a += __shfl_xor(a, 16);
    a += __shfl_xor(a, 32);
    lrow[nj] = a;
  }
  const size_t rbase = (size_t)seg * 32768 + (size_t)bh * 2048 + q0;
#pragma unroll
  for (int o = 0; o < 2; ++o) {
    const int t = o * 16 + c;
#pragma unroll
    for (int dj = 0; dj < 4; ++dj) {
      short4v w;
#pragma unroll
      for (int r = 0; r < 4; ++r) w[r] = f2bf(oacc[dj][o][r]);
      *(short4v*)(OPB + (rbase + t) * 64 + dj * 16 + g * 4) = w;
    }
    if (g == 0) Lb[rbase + t] = lrow[o];
  }
  // drain wrapped prefetch DMAs before wave exit (LDS dealloc hazard)
  asm volatile("s_waitcnt vmcnt(0)" ::: "memory");
}

// ---------------- merge: sum 4 bf16 kv-segment partials -> OB bf16 [(b*2048+t)*512 + h*64+d] ----
__global__ __launch_bounds__(256) void merge_k(const short* __restrict__ OPB, const float* __restrict__ Lb,
                                               short* __restrict__ o) {
  const int gid = blockIdx.x * 256 + threadIdx.x;  // 131072 threads
  const int row = gid >> 2;                        // bh*2048 + s
  const int dg = (gid & 3) * 16;
  float L = 0.f;
#pragma unroll
  for (int s = 0; s < 4; ++s) L += Lb[s * 32768 + row];
  const float rinv = 1.f / L;
  float acc[16];
#pragma unroll
  for (int j = 0; j < 16; ++j) acc[j] = 0.f;
#pragma unroll
  for (int s = 0; s < 4; ++s) {
#pragma unroll
    for (int q = 0; q < 2; ++q) {
      const short8 vv = *(const short8*)(OPB + ((size_t)s * 32768 + row) * 64 + dg + q * 8);
#pragma unroll
      for (int r = 0; r < 8; ++r) acc[q * 8 + r] += bf2f(vv[r]);
    }
  }
  const int bh = row >> 11, srow = row & 2047;
  const int b = bh >> 3, h = bh & 7;
  short8 st[2];
#pragma unroll
  for (int j = 0; j < 16; ++j) st[j >> 3][j & 7] = f2bf(acc[j] * rinv);
  short* dst = o + (size_t)(b * 2048 + srow) * 512 + h * 64 + dg;
  *(short8*)dst = st[0];
  *(short8*)(dst + 8) = st[1];
}

// ---------------- launcher ----------------
extern "C" void kernel_launch(void* const* d_in, const int* in_sizes, int n_in,
                              void* d_out, int out_size, void* d_ws, size_t ws_size,
                              hipStream_t stream) {
  const float* x  = (const float*)d_in[0];
  const float* wq = (const float*)d_in[1];
  const float* bq = (const float*)d_in[2];
  const float* wk = (const float*)d_in[3];
  const float* bk = (const float*)d_in[4];
  const float* wv = (const float*)d_in[5];
  const float* bv = (const float*)d_in[6];
  const float* wo = (const float*)d_in[7];
  const float* bo = (const float*)d_in[8];

  short* XT  = (short*)d_ws;                       // 4096*512 bf16
  short* WQKV = XT + (size_t)4096 * 512;           // 1536*512 (wq|wk|wv)
  short* WO  = WQKV + (size_t)1536 * 512;          // 512*512
  short* QKB = WO + (size_t)512 * 512;             // 4096*1024
  short* VB  = QKB + (size_t)4096 * 1024;          // 512*4096
  short* OB  = VB + (size_t)512 * 4096;            // 4096*512
  short* OPB = OB + (size_t)4096 * 512;            // 4*32768*64 bf16 partial O
  float* Lb  = (float*)(OPB + (size_t)4 * 32768 * 64);  // 4*32768 f32

  prep_k<<<dim3(3072), 256, 0, stream>>>(x, XT, wq, wk, wv, wo, WQKV);
  gemm_bt_k<0><<<dim3(768), 256, 0, stream>>>(WQKV, XT, (void*)QKB, VB, bq, bk, bv);
  attn_k<<<dim3(512), 512, 0, stream>>>(QKB, VB, OPB, Lb);
  merge_k<<<dim3(512), 256, 0, stream>>>(OPB, Lb, OB);
  gemm_bt_k<2><<<dim3(256), 256, 0, stream>>>(OB, WO, d_out, nullptr, bo, nullptr, nullptr);
}